// Round 13
// baseline (347.966 us; speedup 1.0000x reference)
//
#include <hip/hip_runtime.h>
#include <hip/hip_cooperative_groups.h>
#include <math.h>

namespace cg = cooperative_groups;

#define NWIN  4096
#define NHIST 6144                  // 6*1024; float bins (counts exact < 2^24)
// bank-skewed accumulator layout (words):
#define SP_OFF   0                  // sum_p  [0,4096)
#define SPR_OFF  4097               // sum_pr [4097,8193)   bank +1
#define SPD_OFF  8194               // sum_pd [8194,12290)  bank +2
#define HIST_OFF 12292              // hist   [12292,18436)
#define RWORDS   18436              // logical words per replica
#define REP      18464              // replica stride (pad); REP%4==0
#define CE_OFF   RWORDS             // in the flushed copy: 16 wnll + 16 w
#define CW       (RWORDS + 32)      // 18468 words per flushed copy
#define CW4      (CW / 4)           // 4617 float4 groups (exact)
#define CWP      18496              // padded stride (73,984 B; 16B-aligned)
#define CWP4     (CWP / 4)          // 4624
#define NCOPY    256                // fused path: 1 block/CU, one private copy per block
#define NB2      ((CW4 + 63) / 64)  // 73 phase-2 blocks (64 float4 cols each)
#define MAXBLK   256                // fallback path

#define SERVICE    1.0e8f   // CAPACITY * DELTA_T
#define CAPACITY_F 1.0e9f
#define DELTA_T_F  0.1f

// per-row work
__device__ __forceinline__
void row_op(float l0, float l1, int yy, int mk, int wi,
            float dob_raw, float pr_raw, float as_raw,
            float cw0, float cw1, float* L, float& awn, float& aw)
{
    float d = l0 - l1;
    float e = __expf(d);
    float t = __logf(1.0f + e);
    float nll = yy ? t : (t - d);
    float w   = (yy ? cw1 : cw0) * (mk ? 1.0f : 0.0f);
    awn += w * nll;
    aw  += w;
    if (mk && wi >= 0) {
        float p   = 1.0f / (1.0f + e);
        int   seg = (wi < NWIN) ? wi : (NWIN - 1);
        float dob = fmaxf(dob_raw, 0.0f);
        float pr  = fmaxf(pr_raw,  0.0f);
        float as  = fmaxf(as_raw,  0.0f) * 1000.0f;
        unsafeAtomicAdd(&L[SP_OFF  + seg], p);
        unsafeAtomicAdd(&L[SPR_OFF + seg], p * (pr * as));
        unsafeAtomicAdd(&L[SPD_OFF + seg], p * dob);
        int b = (int)(dob * (float)NHIST);
        b = (b < NHIST - 1) ? b : (NHIST - 1);
        b = (b > 0) ? b : 0;
        unsafeAtomicAdd(&L[HIST_OFF + b], 1.0f);
    }
}

// =================== FUSED cooperative kernel: row pass + copy-reduce + finalize ===============
// Grid = 256 blocks x 1024 (1 block/CU, co-resident). Two LDS replicas (R0's measured k1 win).
// Phase 2 replaces pl_kmid with 16-wave blocks doing coalesced 1KB reads (old kmid: 1 wave/SIMD).
// Phase 3 = pl_k2 body on block 0. Zero kernel-boundary gaps.
__global__ __launch_bounds__(1024, 4)
void pl_fused(const float* __restrict__ logits, const int* __restrict__ y,
              const int* __restrict__ mask, const float* __restrict__ x_raw,
              const int* __restrict__ widx, const float* __restrict__ cw,
              float* __restrict__ ws, float* __restrict__ fin,
              float* __restrict__ out, int n)
{
    __shared__ __align__(16) float lds[2 * REP];   // 147,712 B (1 block/CU anyway)
    __shared__ float ce[2][16];
    __shared__ unsigned int sWC[16];
    __shared__ float sWS[16], sWM[16], sV[2], sRed3[3][16];

    const int tid  = threadIdx.x;
    const int lane = tid & 63;

    // ---------------- phase 1: row pass ----------------
    for (int s = tid; s < 2 * REP; s += 1024) lds[s] = 0.0f;
    __syncthreads();

    const float cw0 = cw[0], cw1 = cw[1];
    float awn = 0.0f, aw = 0.0f;
    float* L = lds + (tid >> 9) * REP;   // waves 0-7 -> replica 0, 8-15 -> replica 1

    {
        const int p  = lane & 1;
        const int k  = lane >> 1;
        const int gw = (blockIdx.x * 1024 + tid) >> 6;   // global wave id
        const int nw = gridDim.x * 16;
        const int nt = n >> 7;                           // full 128-row tiles
        const float4* xf4 = (const float4*)x_raw;

        for (int t = gw; t < nt; t += nw) {
            const int W  = t << 7;
            const int b4 = t << 8;                       // 256 float4 per tile
            float4 v0 = xf4[b4 + lane];                  // rows W+ 0..31
            float4 v1 = xf4[b4 + 64  + lane];            // rows W+32..63
            float4 v2 = xf4[b4 + 128 + lane];            // rows W+64..95
            float4 v3 = xf4[b4 + 192 + lane];            // rows W+96..127

            const int rA = W + (p ? 32 : 0) + k;
            const int rB = rA + 64;
            float2 lgA = ((const float2*)logits)[rA];
            float2 lgB = ((const float2*)logits)[rB];
            int yA = y[rA],    yB = y[rB];
            int mA = mask[rA], mB = mask[rB];
            int wA = widx[rA], wB = widx[rB];

            float t0x = __shfl_xor(v0.x, 1, 64);
            float t1z = __shfl_xor(v1.z, 1, 64);
            float t1w = __shfl_xor(v1.w, 1, 64);
            float t2x = __shfl_xor(v2.x, 1, 64);
            float t3z = __shfl_xor(v3.z, 1, 64);
            float t3w = __shfl_xor(v3.w, 1, 64);

            float dobA = p ? t1z : v0.z;
            float prA  = p ? t1w : v0.w;
            float asA  = p ? v1.x : t0x;
            float dobB = p ? t3z : v2.z;
            float prB  = p ? t3w : v2.w;
            float asB  = p ? v3.x : t2x;

            row_op(lgA.x, lgA.y, yA, mA, wA, dobA, prA, asA, cw0, cw1, L, awn, aw);
            row_op(lgB.x, lgB.y, yB, mB, wB, dobB, prB, asB, cw0, cw1, L, awn, aw);
        }
        // tail rows (none when n % 128 == 0)
        if (blockIdx.x == 0 && tid < 64) {
            const int nt7 = nt << 7;
            for (int r = nt7 + lane; r < n; r += 64) {
                float2 lg = ((const float2*)logits)[r];
                const float* xr = x_raw + 8 * (size_t)r;
                row_op(lg.x, lg.y, y[r], mask[r], widx[r], xr[2], xr[3], xr[4],
                       cw0, cw1, L, awn, aw);
            }
        }
    }

    for (int o = 32; o > 0; o >>= 1) {
        awn += __shfl_down(awn, o, 64);
        aw  += __shfl_down(aw,  o, 64);
    }
    if ((tid & 63) == 0) { ce[0][tid >> 6] = awn; ce[1][tid >> 6] = aw; }
    __syncthreads();

    {   // flush replica0+replica1 -> private copy (float4)
        float* cb = ws + (size_t)blockIdx.x * CWP;
        const float4* s0 = (const float4*)lds;
        const float4* s1 = (const float4*)(lds + REP);
        float4* dst = (float4*)cb;
        for (int s = tid; s < RWORDS / 4; s += 1024) {
            float4 a = s0[s], b = s1[s];
            a.x += b.x; a.y += b.y; a.z += b.z; a.w += b.w;
            dst[s] = a;
        }
        if (tid < 16)      cb[CE_OFF + tid] = ce[0][tid];
        else if (tid < 32) cb[CE_OFF + tid] = ce[1][tid - 16];
    }

    cg::grid_group grid = cg::this_grid();
    grid.sync();

    // ---------------- phase 2: reduce NCOPY private copies -> fin ----------------
    if (blockIdx.x < NB2) {
        const int col = blockIdx.x * 64 + lane;      // float4 column
        const int v   = tid >> 6;                    // wave 0..15
        float4 acc = make_float4(0.f, 0.f, 0.f, 0.f);
        if (col < CW4) {
            const float4* pws = (const float4*)ws;
            for (int c = v; c < NCOPY; c += 16) {    // coalesced 1KB reads per wave
                float4 u = pws[(size_t)c * CWP4 + col];
                acc.x += u.x; acc.y += u.y; acc.z += u.z; acc.w += u.w;
            }
        }
        float4* red = (float4*)lds;                  // reuse big LDS (16KB needed)
        red[v * 64 + lane] = acc;
        __syncthreads();
        if (tid < 64) {
            int c2 = blockIdx.x * 64 + tid;
            if (c2 < CW4) {
                float4 r = red[tid];
                for (int w = 1; w < 16; ++w) {
                    float4 u = red[w * 64 + tid];
                    r.x += u.x; r.y += u.y; r.z += u.z; r.w += u.w;
                }
                ((float4*)fin)[c2] = r;
            }
        }
    }
    grid.sync();

    // ---------------- phase 3: quantile + window scan + outputs (block 0) ----------------
    if (blockIdx.x != 0) return;
    {
        const int wv = tid >> 6;
        const float* hist = fin + HIST_OFF;
        const int CHUNK = NHIST / 1024;   // 6 bins per thread

        unsigned int hv[6];
        unsigned int c = 0;
        const int base = tid * CHUNK;
        for (int j = 0; j < CHUNK; ++j) { hv[j] = (unsigned int)hist[base + j]; c += hv[j]; }

        unsigned int vi = c;
        for (int off = 1; off < 64; off <<= 1) {
            unsigned int t = __shfl_up(vi, off, 64);
            if (lane >= off) vi += t;
        }
        if (lane == 63) sWC[wv] = vi;
        if (tid == 0) { sV[0] = 1.0f; sV[1] = 1.0f; }
        __syncthreads();

        unsigned int wbase = 0, nv = 0;
        for (int kk = 0; kk < 16; ++kk) {
            unsigned int t = sWC[kk];
            nv += t;
            if (kk < wv) wbase += t;
        }
        const unsigned int pre = wbase + vi - c;

        float nvf  = (float)nv;
        float pos  = 0.75f * (nvf - 1.0f);
        float fpos = floorf(pos);
        long  lo_l = (long)fpos;
        long  hi_l = (long)ceilf(pos);
        long  nmax = (nv > 0) ? (long)nv - 1 : 0;
        lo_l = lo_l < 0 ? 0 : (lo_l > nmax ? nmax : lo_l);
        hi_l = hi_l < 0 ? 0 : (hi_l > nmax ? nmax : hi_l);
        float frac = pos - fpos;

        if (nv > 0) {
            unsigned int lo = (unsigned int)lo_l, hi = (unsigned int)hi_l;
            if (lo >= pre && lo < pre + c) {
                unsigned int acc = pre;
                for (int j = 0; j < CHUNK; ++j) {
                    acc += hv[j];
                    if (lo < acc) { sV[0] = ((float)(base + j) + 0.5f) * (1.0f / (float)NHIST); break; }
                }
            }
            if (hi >= pre && hi < pre + c) {
                unsigned int acc = pre;
                for (int j = 0; j < CHUNK; ++j) {
                    acc += hv[j];
                    if (hi < acc) { sV[1] = ((float)(base + j) + 0.5f) * (1.0f / (float)NHIST); break; }
                }
            }
        }
        __syncthreads();
        float ref      = sV[0] * (1.0f - frac) + sV[1] * frac;
        float ref_dobs = fmaxf(ref, 1e-6f);
        float inv_ref  = 1.0f / ref_dobs;

        const float* f_sp  = fin + SP_OFF;
        const float* f_spr = fin + SPR_OFF;
        const float* f_spd = fin + SPD_OFF;

        float va[4], vsp[4], vspr[4], vspd[4];
        bool  vinc[4];
        float S = 0.0f, M = -3.0e38f;
        const int w0 = tid * 4;
        for (int j = 0; j < 4; ++j) {
            int   wdx = w0 + j;
            float sp  = f_sp[wdx];
            float spr = f_spr[wdx];
            float spd = f_spd[wdx];
            float a   = spr * DELTA_T_F - SERVICE;
            bool  inc = (sp >= 1e-8f);
            va[j] = a; vsp[j] = sp; vspr[j] = spr; vspd[j] = spd; vinc[j] = inc;
            if (inc) { M = fmaxf(M + a, 0.0f); S = S + a; }
        }

        float s = S, m = M;
        for (int off = 1; off < 64; off <<= 1) {
            float s2 = __shfl_up(s, off, 64);
            float m2 = __shfl_up(m, off, 64);
            if (lane >= off) { m = fmaxf(m2 + s, m); s = s2 + s; }
        }
        if (lane == 63) { sWS[wv] = s; sWM[wv] = m; }
        __syncthreads();
        float ps = 0.0f, pm = -3.0e38f;
        for (int kk = 0; kk < wv; ++kk) { pm = fmaxf(pm + sWS[kk], sWM[kk]); ps += sWS[kk]; }
        float se = __shfl_up(s, 1, 64);
        float me = __shfl_up(m, 1, 64);
        if (lane == 0) { se = 0.0f; me = -3.0e38f; }
        float Me = fmaxf(pm + se, me);
        float Se = ps + se;
        float q  = fmaxf(Se, Me);

        float fsum = 0.0f, lsum = 0.0f, isum = 0.0f;
        for (int j = 0; j < 4; ++j) {
            float qn    = fmaxf(q + va[j], 0.0f);
            float dmean = vspd[j] / (vsp[j] + 1e-6f);
            float dsc   = dmean * inv_ref;
            float oq    = fmaxf(dsc - 1.0f, 0.0f) * SERVICE;
            float fw    = (qn - oq) / (SERVICE + 1e-6f);
            fw = fw * fw;
            float rho = vspr[j] / (CAPACITY_F + 1e-6f);
            rho = fminf(fmaxf(rho, 0.0f), 0.995f);
            float dth = 1.0f / (1.0f - rho + 1e-6f);
            float lt  = fmaxf(dth - dsc, 0.0f);
            if (vinc[j]) { fsum += fw; lsum += lt; isum += 1.0f; q = qn; }
        }

        for (int o = 32; o > 0; o >>= 1) {
            fsum += __shfl_down(fsum, o, 64);
            lsum += __shfl_down(lsum, o, 64);
            isum += __shfl_down(isum, o, 64);
        }
        if ((tid & 63) == 0) { sRed3[0][wv] = fsum; sRed3[1][wv] = lsum; sRed3[2][wv] = isum; }
        __syncthreads();
        if (tid == 0) {
            float F = 0.0f, Lr = 0.0f, I = 0.0f;
            float A = 0.0f, B = 0.0f;
            for (int kk = 0; kk < 16; ++kk) {
                F += sRed3[0][kk]; Lr += sRed3[1][kk]; I += sRed3[2][kk];
                A += fin[CE_OFF + kk]; B += fin[CE_OFF + 16 + kk];
            }
            float l_data = A / B;
            float l_flow = (I > 0.0f) ? F / fmaxf(I, 1.0f) : 0.0f;
            float l_lat  = (I > 0.0f) ? Lr / fmaxf(I, 1.0f) : 0.0f;
            out[0] = l_data + 0.1f * l_flow + 0.1f * l_lat;
            out[1] = l_data;
            out[2] = l_flow;
            out[3] = l_lat;
        }
    }
}

// =================== Fallback path (3 kernels, as R10) ===================
template<int MODE>
__global__ __launch_bounds__(1024, 8)
void pl_k1(const float* __restrict__ logits, const int* __restrict__ y,
           const int* __restrict__ mask, const float* __restrict__ x_raw,
           const int* __restrict__ widx, const float* __restrict__ cw,
           float* __restrict__ ws, int n)
{
    __shared__ __align__(16) float lds[REP];
    __shared__ float ce[2][16];
    const int tid = threadIdx.x;
    for (int s = tid; s < REP; s += 1024) lds[s] = 0.0f;
    __syncthreads();

    const float cw0 = cw[0], cw1 = cw[1];
    float awn = 0.0f, aw = 0.0f;

    const int lane = tid & 63;
    const int p    = lane & 1;
    const int k    = lane >> 1;
    const int gw   = (blockIdx.x * 1024 + tid) >> 6;
    const int nw   = gridDim.x * 16;
    const int nt   = n >> 7;
    const float4* xf4 = (const float4*)x_raw;

    for (int t = gw; t < nt; t += nw) {
        const int W  = t << 7;
        const int b4 = t << 8;
        float4 v0 = xf4[b4 + lane];
        float4 v1 = xf4[b4 + 64  + lane];
        float4 v2 = xf4[b4 + 128 + lane];
        float4 v3 = xf4[b4 + 192 + lane];

        const int rA = W + (p ? 32 : 0) + k;
        const int rB = rA + 64;
        float2 lgA = ((const float2*)logits)[rA];
        float2 lgB = ((const float2*)logits)[rB];
        int yA = y[rA],    yB = y[rB];
        int mA = mask[rA], mB = mask[rB];
        int wA = widx[rA], wB = widx[rB];

        float t0x = __shfl_xor(v0.x, 1, 64);
        float t1z = __shfl_xor(v1.z, 1, 64);
        float t1w = __shfl_xor(v1.w, 1, 64);
        float t2x = __shfl_xor(v2.x, 1, 64);
        float t3z = __shfl_xor(v3.z, 1, 64);
        float t3w = __shfl_xor(v3.w, 1, 64);

        float dobA = p ? t1z : v0.z;
        float prA  = p ? t1w : v0.w;
        float asA  = p ? v1.x : t0x;
        float dobB = p ? t3z : v2.z;
        float prB  = p ? t3w : v2.w;
        float asB  = p ? v3.x : t2x;

        row_op(lgA.x, lgA.y, yA, mA, wA, dobA, prA, asA, cw0, cw1, lds, awn, aw);
        row_op(lgB.x, lgB.y, yB, mB, wB, dobB, prB, asB, cw0, cw1, lds, awn, aw);
    }
    if (blockIdx.x == 0 && tid < 64) {
        for (int r = (nt << 7) + lane; r < n; r += 64) {
            float2 lg = ((const float2*)logits)[r];
            const float* xr = x_raw + 8 * (size_t)r;
            row_op(lg.x, lg.y, y[r], mask[r], widx[r], xr[2], xr[3], xr[4],
                   cw0, cw1, lds, awn, aw);
        }
    }

    for (int o = 32; o > 0; o >>= 1) {
        awn += __shfl_down(awn, o, 64);
        aw  += __shfl_down(aw,  o, 64);
    }
    if ((tid & 63) == 0) { ce[0][tid >> 6] = awn; ce[1][tid >> 6] = aw; }
    __syncthreads();

    if (MODE == 1) {
        float* cb = ws + (size_t)blockIdx.x * CWP;
        const float4* src = (const float4*)lds;
        float4*       dst = (float4*)cb;
        for (int s = tid; s < RWORDS / 4; s += 1024) dst[s] = src[s];
        if (tid < 16)      cb[CE_OFF + tid] = ce[0][tid];
        else if (tid < 32) cb[CE_OFF + tid] = ce[1][tid - 16];
    } else {
        for (int s = tid; s < RWORDS; s += 1024) {
            float v = lds[s];
            if (v != 0.0f) unsafeAtomicAdd(&ws[s], v);
        }
        if (tid < 16)      unsafeAtomicAdd(&ws[CE_OFF + tid], ce[0][tid]);
        else if (tid < 32) unsafeAtomicAdd(&ws[CE_OFF + tid], ce[1][tid - 16]);
    }
}

__global__ __launch_bounds__(256)
void pl_kmid(const float* __restrict__ ws, float* __restrict__ fin, int C)
{
    __shared__ float4 sRed[256];
    const int lane = threadIdx.x & 63;
    const int g    = threadIdx.x >> 6;
    const int idx  = blockIdx.x * 64 + lane;

    float4 a0 = make_float4(0.f, 0.f, 0.f, 0.f);
    float4 a1 = make_float4(0.f, 0.f, 0.f, 0.f);
    if (idx < CW4) {
        const float4* p = (const float4*)ws;
        int c = g;
        for (; c + 4 < C; c += 8) {
            float4 u = p[(size_t)c * CWP4 + idx];
            float4 v = p[(size_t)(c + 4) * CWP4 + idx];
            a0.x += u.x; a0.y += u.y; a0.z += u.z; a0.w += u.w;
            a1.x += v.x; a1.y += v.y; a1.z += v.z; a1.w += v.w;
        }
        for (; c < C; c += 4) {
            float4 u = p[(size_t)c * CWP4 + idx];
            a0.x += u.x; a0.y += u.y; a0.z += u.z; a0.w += u.w;
        }
    }
    a0.x += a1.x; a0.y += a1.y; a0.z += a1.z; a0.w += a1.w;
    sRed[threadIdx.x] = a0;
    __syncthreads();
    if (g == 0 && idx < CW4) {
        float4 r = sRed[lane];
        float4 b = sRed[64 + lane];
        float4 c2 = sRed[128 + lane];
        float4 d = sRed[192 + lane];
        r.x = (r.x + b.x) + (c2.x + d.x);
        r.y = (r.y + b.y) + (c2.y + d.y);
        r.z = (r.z + b.z) + (c2.z + d.z);
        r.w = (r.w + b.w) + (c2.w + d.w);
        ((float4*)fin)[idx] = r;
    }
}

__global__ __launch_bounds__(1024)
void pl_k2(const float* __restrict__ fin, float* __restrict__ out)
{
    __shared__ unsigned int sWC[16];
    __shared__ float        sWS[16];
    __shared__ float        sWM[16];
    __shared__ float        sV[2];
    __shared__ float        sRed[3][16];

    const int tid  = threadIdx.x;
    const int lane = tid & 63;
    const int wv   = tid >> 6;
    const float* hist = fin + HIST_OFF;
    const int CHUNK = NHIST / 1024;

    unsigned int hv[6];
    unsigned int c = 0;
    const int base = tid * CHUNK;
    for (int j = 0; j < CHUNK; ++j) { hv[j] = (unsigned int)hist[base + j]; c += hv[j]; }

    unsigned int vi = c;
    for (int off = 1; off < 64; off <<= 1) {
        unsigned int t = __shfl_up(vi, off, 64);
        if (lane >= off) vi += t;
    }
    if (lane == 63) sWC[wv] = vi;
    if (tid == 0) { sV[0] = 1.0f; sV[1] = 1.0f; }
    __syncthreads();

    unsigned int wbase = 0, nv = 0;
    for (int kk = 0; kk < 16; ++kk) {
        unsigned int t = sWC[kk];
        nv += t;
        if (kk < wv) wbase += t;
    }
    const unsigned int pre = wbase + vi - c;

    float nvf  = (float)nv;
    float pos  = 0.75f * (nvf - 1.0f);
    float fpos = floorf(pos);
    long  lo_l = (long)fpos;
    long  hi_l = (long)ceilf(pos);
    long  nmax = (nv > 0) ? (long)nv - 1 : 0;
    lo_l = lo_l < 0 ? 0 : (lo_l > nmax ? nmax : lo_l);
    hi_l = hi_l < 0 ? 0 : (hi_l > nmax ? nmax : hi_l);
    float frac = pos - fpos;

    if (nv > 0) {
        unsigned int lo = (unsigned int)lo_l, hi = (unsigned int)hi_l;
        if (lo >= pre && lo < pre + c) {
            unsigned int acc = pre;
            for (int j = 0; j < CHUNK; ++j) {
                acc += hv[j];
                if (lo < acc) { sV[0] = ((float)(base + j) + 0.5f) * (1.0f / (float)NHIST); break; }
            }
        }
        if (hi >= pre && hi < pre + c) {
            unsigned int acc = pre;
            for (int j = 0; j < CHUNK; ++j) {
                acc += hv[j];
                if (hi < acc) { sV[1] = ((float)(base + j) + 0.5f) * (1.0f / (float)NHIST); break; }
            }
        }
    }
    __syncthreads();
    float ref      = sV[0] * (1.0f - frac) + sV[1] * frac;
    float ref_dobs = fmaxf(ref, 1e-6f);
    float inv_ref  = 1.0f / ref_dobs;

    const float* f_sp  = fin + SP_OFF;
    const float* f_spr = fin + SPR_OFF;
    const float* f_spd = fin + SPD_OFF;

    float va[4], vsp[4], vspr[4], vspd[4];
    bool  vinc[4];
    float S = 0.0f, M = -3.0e38f;
    const int w0 = tid * 4;
    for (int j = 0; j < 4; ++j) {
        int   wdx = w0 + j;
        float sp  = f_sp[wdx];
        float spr = f_spr[wdx];
        float spd = f_spd[wdx];
        float a   = spr * DELTA_T_F - SERVICE;
        bool  inc = (sp >= 1e-8f);
        va[j] = a; vsp[j] = sp; vspr[j] = spr; vspd[j] = spd; vinc[j] = inc;
        if (inc) { M = fmaxf(M + a, 0.0f); S = S + a; }
    }

    float s = S, m = M;
    for (int off = 1; off < 64; off <<= 1) {
        float s2 = __shfl_up(s, off, 64);
        float m2 = __shfl_up(m, off, 64);
        if (lane >= off) { m = fmaxf(m2 + s, m); s = s2 + s; }
    }
    if (lane == 63) { sWS[wv] = s; sWM[wv] = m; }
    __syncthreads();
    float ps = 0.0f, pm = -3.0e38f;
    for (int kk = 0; kk < wv; ++kk) { pm = fmaxf(pm + sWS[kk], sWM[kk]); ps += sWS[kk]; }
    float se = __shfl_up(s, 1, 64);
    float me = __shfl_up(m, 1, 64);
    if (lane == 0) { se = 0.0f; me = -3.0e38f; }
    float Me = fmaxf(pm + se, me);
    float Se = ps + se;
    float q  = fmaxf(Se, Me);

    float fsum = 0.0f, lsum = 0.0f, isum = 0.0f;
    for (int j = 0; j < 4; ++j) {
        float qn    = fmaxf(q + va[j], 0.0f);
        float dmean = vspd[j] / (vsp[j] + 1e-6f);
        float dsc   = dmean * inv_ref;
        float oq    = fmaxf(dsc - 1.0f, 0.0f) * SERVICE;
        float fw    = (qn - oq) / (SERVICE + 1e-6f);
        fw = fw * fw;
        float rho = vspr[j] / (CAPACITY_F + 1e-6f);
        rho = fminf(fmaxf(rho, 0.0f), 0.995f);
        float dth = 1.0f / (1.0f - rho + 1e-6f);
        float lt  = fmaxf(dth - dsc, 0.0f);
        if (vinc[j]) { fsum += fw; lsum += lt; isum += 1.0f; q = qn; }
    }

    for (int o = 32; o > 0; o >>= 1) {
        fsum += __shfl_down(fsum, o, 64);
        lsum += __shfl_down(lsum, o, 64);
        isum += __shfl_down(isum, o, 64);
    }
    if ((tid & 63) == 0) { sRed[0][wv] = fsum; sRed[1][wv] = lsum; sRed[2][wv] = isum; }
    __syncthreads();
    if (tid == 0) {
        float F = 0.0f, L = 0.0f, I = 0.0f;
        float A = 0.0f, B = 0.0f;
        for (int kk = 0; kk < 16; ++kk) {
            F += sRed[0][kk]; L += sRed[1][kk]; I += sRed[2][kk];
            A += fin[CE_OFF + kk]; B += fin[CE_OFF + 16 + kk];
        }
        float l_data = A / B;
        float l_flow = (I > 0.0f) ? F / fmaxf(I, 1.0f) : 0.0f;
        float l_lat  = (I > 0.0f) ? L / fmaxf(I, 1.0f) : 0.0f;
        out[0] = l_data + 0.1f * l_flow + 0.1f * l_lat;
        out[1] = l_data;
        out[2] = l_flow;
        out[3] = l_lat;
    }
}

extern "C" void kernel_launch(void* const* d_in, const int* in_sizes, int n_in,
                              void* d_out, int out_size, void* d_ws, size_t ws_size,
                              hipStream_t stream) {
    const float* logits = (const float*)d_in[0];
    const int*   y      = (const int*)d_in[1];
    const int*   mask   = (const int*)d_in[2];
    const float* x_raw  = (const float*)d_in[3];
    const int*   widx   = (const int*)d_in[4];
    const float* cw     = (const float*)d_in[5];
    float* out = (float*)d_out;
    int n = in_sizes[1];   // N from y

    float* ws = (float*)d_ws;
    size_t words = ws_size / 4;
    long   cap   = (words > CW) ? (long)((words - CW) / CWP) : 0;

    if (cap >= NCOPY) {
        // fused cooperative path: 256 blocks (1/CU, co-resident), zero kernel boundaries
        float* fin = ws + (size_t)NCOPY * CWP;
        void* args[] = { (void*)&logits, (void*)&y, (void*)&mask, (void*)&x_raw,
                         (void*)&widx, (void*)&cw, (void*)&ws, (void*)&fin,
                         (void*)&out, (void*)&n };
        hipLaunchCooperativeKernel((void*)pl_fused, dim3(NCOPY), dim3(1024),
                                   args, 0, stream);
    } else if (cap >= 64) {
        int nblk = (cap > MAXBLK) ? MAXBLK : (int)cap;
        float* fin = ws + (size_t)nblk * CWP;
        hipLaunchKernelGGL((pl_k1<1>), dim3(nblk), dim3(1024), 0, stream,
                           logits, y, mask, x_raw, widx, cw, ws, n);
        hipLaunchKernelGGL(pl_kmid, dim3((CW4 + 63) / 64), dim3(256), 0, stream,
                           ws, fin, nblk);
        hipLaunchKernelGGL(pl_k2, dim3(1), dim3(1024), 0, stream,
                           fin, out);
    } else {
        hipMemsetAsync(d_ws, 0, (size_t)CW * 4, stream);
        hipLaunchKernelGGL((pl_k1<0>), dim3(256), dim3(1024), 0, stream,
                           logits, y, mask, x_raw, widx, cw, ws, n);
        hipLaunchKernelGGL(pl_k2, dim3(1), dim3(1024), 0, stream,
                           ws, out);
    }
}

// Round 16
// 274.484 us; speedup vs baseline: 1.2677x; 1.2677x over previous
//
#include <hip/hip_runtime.h>
#include <math.h>

#define NWIN  4096
#define NHIST 6144                  // 6*1024; float bins (counts exact < 2^24)
// bank-skewed accumulator layout (words):
#define SP_OFF   0                  // sum_p  [0,4096)
#define SPR_OFF  4097               // sum_pr [4097,8193)   bank +1
#define SPD_OFF  8194               // sum_pd [8194,12290)  bank +2
#define HIST_OFF 12292              // hist   [12292,18436)
#define RWORDS   18436              // logical words per replica
#define REP      18464              // replica stride (pad); REP%4==0
#define CE_OFF   RWORDS             // in the flushed copy: 16 wnll + 16 w
#define CW       (RWORDS + 32)      // 18468 words per flushed copy
#define CW4      (CW / 4)           // 4617 float4 groups (exact)
#define CWP      18496              // padded stride (73,984 B; 16B-aligned)
#define CWP4     (CWP / 4)          // 4624
#define MAXBLK   256                // 1 block/CU (148KB LDS forces it anyway)

#define SERVICE    1.0e8f   // CAPACITY * DELTA_T
#define CAPACITY_F 1.0e9f
#define DELTA_T_F  0.1f

// per-row work
__device__ __forceinline__
void row_op(float l0, float l1, int yy, int mk, int wi,
            float dob_raw, float pr_raw, float as_raw,
            float cw0, float cw1, float* L, float& awn, float& aw)
{
    float d = l0 - l1;
    float e = __expf(d);
    float t = __logf(1.0f + e);
    float nll = yy ? t : (t - d);
    float w   = (yy ? cw1 : cw0) * (mk ? 1.0f : 0.0f);
    awn += w * nll;
    aw  += w;
    if (mk && wi >= 0) {
        float p   = 1.0f / (1.0f + e);
        int   seg = (wi < NWIN) ? wi : (NWIN - 1);
        float dob = fmaxf(dob_raw, 0.0f);
        float pr  = fmaxf(pr_raw,  0.0f);
        float as  = fmaxf(as_raw,  0.0f) * 1000.0f;
        // 3 adds hit banks b, b+1, b+2 (skewed offsets) — no intra-row same-bank serialize
        unsafeAtomicAdd(&L[SP_OFF  + seg], p);
        unsafeAtomicAdd(&L[SPR_OFF + seg], p * (pr * as));
        unsafeAtomicAdd(&L[SPD_OFF + seg], p * dob);
        int b = (int)(dob * (float)NHIST);
        b = (b < NHIST - 1) ? b : (NHIST - 1);
        b = (b > 0) ? b : 0;
        unsafeAtomicAdd(&L[HIST_OFF + b], 1.0f);
    }
}

// ---------------- K1: R0's measured-best structure (93us) + 2-way far-row unroll ----------------
// Grid-stride per-thread rows (R0's access pattern verbatim), TWO LDS replicas (waves 0-7 ->
// replica 0, 8-15 -> replica 1 — the only lever that ever improved k1), 2-way unroll over rows
// i and i+S (far apart, independent) to double loads in flight without changing coalescing.
// MODE 1: float4 flush of (rep0+rep1) to private copy. MODE 0: atomic fallback into ws[0].
template<int MODE>
__global__ __launch_bounds__(1024)
void pl_k1(const float* __restrict__ logits, const int* __restrict__ y,
           const int* __restrict__ mask, const float* __restrict__ x_raw,
           const int* __restrict__ widx, const float* __restrict__ cw,
           float* __restrict__ ws, int n)
{
    __shared__ __align__(16) float lds[2 * REP];   // 147,712 B -> 1 block/CU (16 waves)
    __shared__ float ce[2][16];
    const int tid = threadIdx.x;
    for (int s = tid; s < 2 * REP; s += 1024) lds[s] = 0.0f;
    __syncthreads();

    const float cw0 = cw[0], cw1 = cw[1];
    float awn = 0.0f, aw = 0.0f;

    float* L = lds + (tid >> 9) * REP;  // waves 0-7 -> replica 0, waves 8-15 -> replica 1

    const int S = gridDim.x * 1024;
    int i = blockIdx.x * 1024 + tid;
    for (; i + S < n; i += 2 * S) {
        const int j = i + S;
        // both iterations' loads issued back-to-back (independent, far-apart rows)
        float2 lg0 = ((const float2*)logits)[i];
        float2 lg1 = ((const float2*)logits)[j];
        int    y0  = y[i],    y1  = y[j];
        int    m0  = mask[i], m1  = mask[j];
        int    w0  = widx[i], w1  = widx[j];
        float2 xa0 = *(const float2*)(x_raw + 8 * (size_t)i + 2);
        float  x40 = x_raw[8 * (size_t)i + 4];
        float2 xa1 = *(const float2*)(x_raw + 8 * (size_t)j + 2);
        float  x41 = x_raw[8 * (size_t)j + 4];
        row_op(lg0.x, lg0.y, y0, m0, w0, xa0.x, xa0.y, x40, cw0, cw1, L, awn, aw);
        row_op(lg1.x, lg1.y, y1, m1, w1, xa1.x, xa1.y, x41, cw0, cw1, L, awn, aw);
    }
    for (; i < n; i += S) {
        float2 lg  = ((const float2*)logits)[i];
        float2 xa  = *(const float2*)(x_raw + 8 * (size_t)i + 2);
        float  x4  = x_raw[8 * (size_t)i + 4];
        row_op(lg.x, lg.y, y[i], mask[i], widx[i], xa.x, xa.y, x4, cw0, cw1, L, awn, aw);
    }

    for (int o = 32; o > 0; o >>= 1) {
        awn += __shfl_down(awn, o, 64);
        aw  += __shfl_down(aw,  o, 64);
    }
    if ((tid & 63) == 0) { ce[0][tid >> 6] = awn; ce[1][tid >> 6] = aw; }
    __syncthreads();

    if (MODE == 1) {
        float* cb = ws + (size_t)blockIdx.x * CWP;
        const float4* s0 = (const float4*)lds;
        const float4* s1 = (const float4*)(lds + REP);
        float4* dst = (float4*)cb;
        for (int s = tid; s < RWORDS / 4; s += 1024) {
            float4 a = s0[s], b = s1[s];
            a.x += b.x; a.y += b.y; a.z += b.z; a.w += b.w;
            dst[s] = a;
        }
        if (tid < 16)      cb[CE_OFF + tid] = ce[0][tid];
        else if (tid < 32) cb[CE_OFF + tid] = ce[1][tid - 16];
    } else {
        for (int s = tid; s < RWORDS; s += 1024) {
            float v = lds[s] + lds[REP + s];
            if (v != 0.0f) unsafeAtomicAdd(&ws[s], v);
        }
        if (tid < 16)      unsafeAtomicAdd(&ws[CE_OFF + tid], ce[0][tid]);
        else if (tid < 32) unsafeAtomicAdd(&ws[CE_OFF + tid], ce[1][tid - 16]);
    }
}

// ---------------- Kmid: reduce C private copies into fin (float4, 4-way c-split) ----------------
__global__ __launch_bounds__(256)
void pl_kmid(const float* __restrict__ ws, float* __restrict__ fin, int C)
{
    __shared__ float4 sRed[256];
    const int lane = threadIdx.x & 63;
    const int g    = threadIdx.x >> 6;          // c-group 0..3
    const int idx  = blockIdx.x * 64 + lane;    // float4 index into copy

    float4 a0 = make_float4(0.f, 0.f, 0.f, 0.f);
    float4 a1 = make_float4(0.f, 0.f, 0.f, 0.f);
    if (idx < CW4) {
        const float4* p = (const float4*)ws;
        int c = g;
        for (; c + 4 < C; c += 8) {
            float4 u = p[(size_t)c * CWP4 + idx];
            float4 v = p[(size_t)(c + 4) * CWP4 + idx];
            a0.x += u.x; a0.y += u.y; a0.z += u.z; a0.w += u.w;
            a1.x += v.x; a1.y += v.y; a1.z += v.z; a1.w += v.w;
        }
        for (; c < C; c += 4) {
            float4 u = p[(size_t)c * CWP4 + idx];
            a0.x += u.x; a0.y += u.y; a0.z += u.z; a0.w += u.w;
        }
    }
    a0.x += a1.x; a0.y += a1.y; a0.z += a1.z; a0.w += a1.w;
    sRed[threadIdx.x] = a0;
    __syncthreads();
    if (g == 0 && idx < CW4) {
        float4 r = sRed[lane];
        float4 b = sRed[64 + lane];
        float4 c2 = sRed[128 + lane];
        float4 d = sRed[192 + lane];
        r.x = (r.x + b.x) + (c2.x + d.x);
        r.y = (r.y + b.y) + (c2.y + d.y);
        r.z = (r.z + b.z) + (c2.z + d.z);
        r.w = (r.w + b.w) + (c2.w + d.w);
        ((float4*)fin)[idx] = r;
    }
}

// ---------------- K2: quantile + parallel window scan + outputs ----------------
// Wave-shuffle scans (4 barriers total).
__global__ __launch_bounds__(1024)
void pl_k2(const float* __restrict__ fin, float* __restrict__ out)
{
    __shared__ unsigned int sWC[16];
    __shared__ float        sWS[16];
    __shared__ float        sWM[16];
    __shared__ float        sV[2];
    __shared__ float        sRed[3][16];

    const int tid  = threadIdx.x;
    const int lane = tid & 63;
    const int wv   = tid >> 6;
    const float* hist = fin + HIST_OFF;
    const int CHUNK = NHIST / 1024;   // 6 bins per thread

    unsigned int hv[6];
    unsigned int c = 0;
    const int base = tid * CHUNK;
    for (int j = 0; j < CHUNK; ++j) { hv[j] = (unsigned int)hist[base + j]; c += hv[j]; }

    // wave inclusive scan of counts
    unsigned int vi = c;
    for (int off = 1; off < 64; off <<= 1) {
        unsigned int t = __shfl_up(vi, off, 64);
        if (lane >= off) vi += t;
    }
    if (lane == 63) sWC[wv] = vi;
    if (tid == 0) { sV[0] = 1.0f; sV[1] = 1.0f; }
    __syncthreads();

    unsigned int wbase = 0, nv = 0;
    for (int kk = 0; kk < 16; ++kk) {
        unsigned int t = sWC[kk];
        nv += t;
        if (kk < wv) wbase += t;
    }
    const unsigned int pre = wbase + vi - c;   // exclusive prefix for this thread

    float nvf  = (float)nv;
    float pos  = 0.75f * (nvf - 1.0f);
    float fpos = floorf(pos);
    long  lo_l = (long)fpos;
    long  hi_l = (long)ceilf(pos);
    long  nmax = (nv > 0) ? (long)nv - 1 : 0;
    lo_l = lo_l < 0 ? 0 : (lo_l > nmax ? nmax : lo_l);
    hi_l = hi_l < 0 ? 0 : (hi_l > nmax ? nmax : hi_l);
    float frac = pos - fpos;

    if (nv > 0) {
        unsigned int lo = (unsigned int)lo_l, hi = (unsigned int)hi_l;
        if (lo >= pre && lo < pre + c) {
            unsigned int acc = pre;
            for (int j = 0; j < CHUNK; ++j) {
                acc += hv[j];
                if (lo < acc) { sV[0] = ((float)(base + j) + 0.5f) * (1.0f / (float)NHIST); break; }
            }
        }
        if (hi >= pre && hi < pre + c) {
            unsigned int acc = pre;
            for (int j = 0; j < CHUNK; ++j) {
                acc += hv[j];
                if (hi < acc) { sV[1] = ((float)(base + j) + 0.5f) * (1.0f / (float)NHIST); break; }
            }
        }
    }
    __syncthreads();
    float ref      = sV[0] * (1.0f - frac) + sV[1] * frac;
    float ref_dobs = fmaxf(ref, 1e-6f);
    float inv_ref  = 1.0f / ref_dobs;

    const float* f_sp  = fin + SP_OFF;
    const float* f_spr = fin + SPR_OFF;
    const float* f_spd = fin + SPD_OFF;

    float va[4], vsp[4], vspr[4], vspd[4];
    bool  vinc[4];
    float S = 0.0f, M = -3.0e38f;
    const int w0 = tid * 4;
    for (int j = 0; j < 4; ++j) {
        int   wdx = w0 + j;
        float sp  = f_sp[wdx];
        float spr = f_spr[wdx];
        float spd = f_spd[wdx];
        float a   = spr * DELTA_T_F - SERVICE;
        bool  inc = (sp >= 1e-8f);   // == (cnt>=1 && sp>=1e-8)
        va[j] = a; vsp[j] = sp; vspr[j] = spr; vspd[j] = spd; vinc[j] = inc;
        if (inc) { M = fmaxf(M + a, 0.0f); S = S + a; }
    }

    // wave inclusive max-plus scan: (S1,M1)⊕(S2,M2) = (S1+S2, max(M1+S2, M2))
    float s = S, m = M;
    for (int off = 1; off < 64; off <<= 1) {
        float s2 = __shfl_up(s, off, 64);
        float m2 = __shfl_up(m, off, 64);
        if (lane >= off) { m = fmaxf(m2 + s, m); s = s2 + s; }
    }
    if (lane == 63) { sWS[wv] = s; sWM[wv] = m; }
    __syncthreads();
    float ps = 0.0f, pm = -3.0e38f;
    for (int kk = 0; kk < wv; ++kk) { pm = fmaxf(pm + sWS[kk], sWM[kk]); ps += sWS[kk]; }
    float se = __shfl_up(s, 1, 64);
    float me = __shfl_up(m, 1, 64);
    if (lane == 0) { se = 0.0f; me = -3.0e38f; }
    float Me = fmaxf(pm + se, me);
    float Se = ps + se;
    float q  = fmaxf(Se, Me);   // queue state entering this thread's 4 windows (q0=0)

    float fsum = 0.0f, lsum = 0.0f, isum = 0.0f;
    for (int j = 0; j < 4; ++j) {
        float qn    = fmaxf(q + va[j], 0.0f);
        float dmean = vspd[j] / (vsp[j] + 1e-6f);
        float dsc   = dmean * inv_ref;
        float oq    = fmaxf(dsc - 1.0f, 0.0f) * SERVICE;
        float fw    = (qn - oq) / (SERVICE + 1e-6f);
        fw = fw * fw;
        float rho = vspr[j] / (CAPACITY_F + 1e-6f);
        rho = fminf(fmaxf(rho, 0.0f), 0.995f);
        float dth = 1.0f / (1.0f - rho + 1e-6f);
        float lt  = fmaxf(dth - dsc, 0.0f);
        if (vinc[j]) { fsum += fw; lsum += lt; isum += 1.0f; q = qn; }
    }

    for (int o = 32; o > 0; o >>= 1) {
        fsum += __shfl_down(fsum, o, 64);
        lsum += __shfl_down(lsum, o, 64);
        isum += __shfl_down(isum, o, 64);
    }
    if ((tid & 63) == 0) { sRed[0][wv] = fsum; sRed[1][wv] = lsum; sRed[2][wv] = isum; }
    __syncthreads();
    if (tid == 0) {
        float F = 0.0f, L = 0.0f, I = 0.0f;
        float A = 0.0f, B = 0.0f;
        for (int kk = 0; kk < 16; ++kk) {
            F += sRed[0][kk]; L += sRed[1][kk]; I += sRed[2][kk];
            A += fin[CE_OFF + kk]; B += fin[CE_OFF + 16 + kk];
        }
        float l_data = A / B;
        float l_flow = (I > 0.0f) ? F / fmaxf(I, 1.0f) : 0.0f;
        float l_lat  = (I > 0.0f) ? L / fmaxf(I, 1.0f) : 0.0f;
        out[0] = l_data + 0.1f * l_flow + 0.1f * l_lat;
        out[1] = l_data;
        out[2] = l_flow;
        out[3] = l_lat;
    }
}

extern "C" void kernel_launch(void* const* d_in, const int* in_sizes, int n_in,
                              void* d_out, int out_size, void* d_ws, size_t ws_size,
                              hipStream_t stream) {
    const float* logits = (const float*)d_in[0];
    const int*   y      = (const int*)d_in[1];
    const int*   mask   = (const int*)d_in[2];
    const float* x_raw  = (const float*)d_in[3];
    const int*   widx   = (const int*)d_in[4];
    const float* cw     = (const float*)d_in[5];
    float* out = (float*)d_out;
    int n = in_sizes[1];   // N from y

    float* ws = (float*)d_ws;
    size_t words = ws_size / 4;
    long   cap   = (words > CW) ? (long)((words - CW) / CWP) : 0;
    int    nblk  = (cap > MAXBLK) ? MAXBLK : (int)cap;

    if (nblk >= 64) {
        float* fin = ws + (size_t)nblk * CWP;
        hipLaunchKernelGGL((pl_k1<1>), dim3(nblk), dim3(1024), 0, stream,
                           logits, y, mask, x_raw, widx, cw, ws, n);
        hipLaunchKernelGGL(pl_kmid, dim3((CW4 + 63) / 64), dim3(256), 0, stream,
                           ws, fin, nblk);
        hipLaunchKernelGGL(pl_k2, dim3(1), dim3(1024), 0, stream,
                           fin, out);
    } else {
        hipMemsetAsync(d_ws, 0, (size_t)CW * 4, stream);
        hipLaunchKernelGGL((pl_k1<0>), dim3(256), dim3(1024), 0, stream,
                           logits, y, mask, x_raw, widx, cw, ws, n);
        hipLaunchKernelGGL(pl_k2, dim3(1), dim3(1024), 0, stream,
                           ws, out);
    }
}